// Round 6
// baseline (923.575 us; speedup 1.0000x reference)
//
#include <hip/hip_runtime.h>
#include <cstdint>

// Problem: input [32,64,64,256] fp32 = 131072 rows x 256; embed [256,2048] fp32.
// d_out (fp32): quantize[33554432] | diff[1] | embed_ind_as_float[131072]
//
// Strategy: split-bf16 MFMA distance GEMM (xh+xl)(eh+el) with 3 MFMA terms,
// per-row top-2 candidate tracking, then exact fp32 refine of the 2 candidates
// fused with the gather/straight-through/diff epilogue.
//
// R1: NT loads on streaming input (kept).
// R3: swapped MFMA operands (codes=A/M, rows=B/N) -> lane-local top-2.
// R4: 32x32x16 MFMA -> halved fragments, 2 rows/lane state.
// R5: explicit 2-deep software pipeline in the k-loop.
// R6: pin amdgpu_waves_per_eu(2,2) on pass1. Evidence: VGPR_Count stayed
//     EXACTLY 128 (= 64 acc + 64 arch) across R3/R4/R5 while spill traffic
//     (WRITE 269-615 MB vs 0.5 MB real stores) shrank only proportionally
//     to state size -> the allocator's BUDGET, not demand, is the binding
//     constraint. launch_bounds(,2) only sets a min; the allocator chases
//     4 waves/EU (128-reg step) that the 64 KB LDS makes unreachable
//     (2 blocks/CU hard cap). Pinning max=2 waves/EU gives 256 regs/wave:
//     pipeline buffers + state fit, spills vanish, codebook stays L2-hot.

#define NROWS   131072
#define DIM     256
#define NE      2048
#define BM      64                    // rows per pass1 block
#define NBLK_P1 (NROWS / BM)          // 2048
#define GROWS   4
#define NBLK_RG (NROWS / GROWS)       // 32768

typedef __attribute__((ext_vector_type(8))) short bf16x8;
typedef __attribute__((ext_vector_type(4))) float f32x4;
typedef __attribute__((ext_vector_type(16))) float f32x16;

__device__ __forceinline__ ushort bf16_rne(float v) {
  uint u = __float_as_uint(v);
  return (ushort)((u + 0x7FFFu + ((u >> 16) & 1u)) >> 16);
}
__device__ __forceinline__ void split_hi_lo(float v, ushort& h, ushort& l) {
  h = bf16_rne(v);
  const float hf = __uint_as_float(((uint)h) << 16);
  l = bf16_rne(v - hf);
}

// ---------------------------------------------------------------------------
// enorm[j] = sum_d embed[d][j]^2
// ---------------------------------------------------------------------------
__global__ __launch_bounds__(256) void enorm_kernel(
    const float* __restrict__ embed, float* __restrict__ enorm) {
  const int j = blockIdx.x * 256 + threadIdx.x;
  float s = 0.f;
#pragma unroll 8
  for (int d = 0; d < DIM; ++d) {
    const float v = embed[(size_t)d * NE + j];
    s = fmaf(v, v, s);
  }
  enorm[j] = s;
}

// ---------------------------------------------------------------------------
// embT[j][d] = embed[d][j]
// ---------------------------------------------------------------------------
__global__ __launch_bounds__(256) void transpose_kernel(
    const float* __restrict__ embed, float* __restrict__ embT) {
  __shared__ float tile[32][33];
  const int tx = threadIdx.x;  // 0..31
  const int ty = threadIdx.y;  // 0..7
  const int j0 = blockIdx.x * 32;
  const int d0 = blockIdx.y * 32;
#pragma unroll
  for (int i = 0; i < 4; ++i) {
    const int dd = ty + i * 8;
    tile[dd][tx] = embed[(size_t)(d0 + dd) * NE + j0 + tx];
  }
  __syncthreads();
#pragma unroll
  for (int i = 0; i < 4; ++i) {
    const int jj = ty + i * 8;
    embT[(size_t)(j0 + jj) * DIM + d0 + tx] = tile[tx][jj];
  }
}

// ---------------------------------------------------------------------------
// Pack embed into bf16 hi/lo in 32x32x16 MFMA fragment order:
// ebh4[(ct*16+ks)*64 + lane] = 8 bf16 of code ct*32+(lane&31),
//                              k = ks*16 + (lane>>5)*8 .. +7
// ---------------------------------------------------------------------------
__global__ __launch_bounds__(256) void pack_embed_kernel(
    const float* __restrict__ embT, uint4* __restrict__ ebh4,
    uint4* __restrict__ ebl4) {
  const int g    = blockIdx.x * 256 + threadIdx.x;  // 0..65535
  const int ct   = g >> 10;        // code tile of 32 (0..63)
  const int r    = g & 1023;
  const int ks   = r >> 6;         // k-step of 16 (0..15)
  const int lane = r & 63;
  const int code = ct * 32 + (lane & 31);
  const int k0   = ks * 16 + (lane >> 5) * 8;
  const float* src = embT + (size_t)code * DIM + k0;
  const float4 a = *(const float4*)(src);
  const float4 b = *(const float4*)(src + 4);
  ushort h[8], l[8];
  split_hi_lo(a.x, h[0], l[0]); split_hi_lo(a.y, h[1], l[1]);
  split_hi_lo(a.z, h[2], l[2]); split_hi_lo(a.w, h[3], l[3]);
  split_hi_lo(b.x, h[4], l[4]); split_hi_lo(b.y, h[5], l[5]);
  split_hi_lo(b.z, h[6], l[6]); split_hi_lo(b.w, h[7], l[7]);
  uint4 hv, lv;
  hv.x = (uint)h[0] | ((uint)h[1] << 16); hv.y = (uint)h[2] | ((uint)h[3] << 16);
  hv.z = (uint)h[4] | ((uint)h[5] << 16); hv.w = (uint)h[6] | ((uint)h[7] << 16);
  lv.x = (uint)l[0] | ((uint)l[1] << 16); lv.y = (uint)l[2] | ((uint)l[3] << 16);
  lv.z = (uint)l[4] | ((uint)l[5] << 16); lv.w = (uint)l[6] | ((uint)l[7] << 16);
  ebh4[g] = hv;
  ebl4[g] = lv;
}

// ---------------------------------------------------------------------------
// Pass 1: split-bf16 32x32x16 MFMA distance GEMM + per-row top-2, software-
// pipelined. Block = 256 thr (4 waves), 64 rows staged in LDS (hi/lo, frag
// order). Wave w owns codes [w*512, w*512+512) in 8 chunks of 64 (2 tiles).
// Pipeline: two fragment buffer sets (A/B) alternate by compile-time parity;
// each slot prefetches the next k-step's 4 global + 4 LDS b128 before the
// 12-MFMA cluster of the current one.
// ---------------------------------------------------------------------------
__global__ __launch_bounds__(256)
__attribute__((amdgpu_waves_per_eu(2, 2))) void pass1_kernel(
    const float* __restrict__ inp, const uint4* __restrict__ ebh4,
    const uint4* __restrict__ ebl4, const float* __restrict__ enorm,
    uint* __restrict__ cand) {
  __shared__ __align__(16) uint smem[16384];  // 64 KB
  ushort* AhL = (ushort*)smem;                // 32 KB (input rows, hi)
  ushort* AlL = AhL + 16384;                  // 32 KB (input rows, lo)
  const int t  = threadIdx.x;
  const int r0 = blockIdx.x * BM;

  // Stage input rows: fp32 -> bf16 hi/lo, 32x32x16 fragment layout:
  // element (row, k): nt=row>>5, ks=k>>4, kh=(k>>3)&1, j=k&7
  // idx = ((nt*16+ks)*64 + (row&31) + kh*32)*8 + j
  {
    const int row = t >> 2, kq = t & 3;
    const int nt = row >> 5, r31 = row & 31;
    const f32x4* src = (const f32x4*)(inp + (size_t)(r0 + row) * DIM);
#pragma unroll 4
    for (int c = 0; c < 16; ++c) {
      const int k4 = c * 4 + kq;
      const f32x4 v = __builtin_nontemporal_load(src + k4);  // NT: stream input
      const int k = k4 * 4;
      const int ks = k >> 4, kh = (k >> 3) & 1, j = k & 7;
      const int idx = ((nt * 16 + ks) * 64 + r31 + kh * 32) * 8 + j;
      ushort h0, h1, h2, h3, l0, l1, l2, l3;
      split_hi_lo(v[0], h0, l0); split_hi_lo(v[1], h1, l1);
      split_hi_lo(v[2], h2, l2); split_hi_lo(v[3], h3, l3);
      ushort4 hv; hv.x = h0; hv.y = h1; hv.z = h2; hv.w = h3;
      ushort4 lv; lv.x = l0; lv.y = l1; lv.z = l2; lv.w = l3;
      *(ushort4*)(AhL + idx) = hv;
      *(ushort4*)(AlL + idx) = lv;
    }
  }
  __syncthreads();

  const int wv = t >> 6, lane = t & 63;
  const int go2 = lane >> 5;  // 4-code offset within reg-mapped codes

  // Per-lane top-2 state for 2 rows (row = nt*32 + (lane&31)): 8 regs.
  float D1[2], D2[2];
  uint  I1[2], I2[2];
#pragma unroll
  for (int i = 0; i < 2; ++i) {
    D1[i] = 3.4e38f; D2[i] = 3.4e38f; I1[i] = 0xFFFFu; I2[i] = 0xFFFFu;
  }

  // Fragment loaders. Code frag addr:
  //   bi = (wv*16 + ch*2 + ct)*1024 + ks*64 + lane   (uint4 index)
  // Row frag addr (ushort index):
  //   ai = ((nt*16 + ks)*64 + lane)*8
  auto loadCodes = [&](int ch, int ks, bf16x8* ch_, bf16x8* cl_) {
#pragma unroll
    for (int ct = 0; ct < 2; ++ct) {
      const int bi = (wv * 16 + ch * 2 + ct) * 1024 + ks * 64 + lane;
      ch_[ct] = *(const bf16x8*)(ebh4 + bi);
      cl_[ct] = *(const bf16x8*)(ebl4 + bi);
    }
  };
  auto loadRows = [&](int ks, bf16x8* rh_, bf16x8* rl_) {
#pragma unroll
    for (int nt = 0; nt < 2; ++nt) {
      const int ai = ((nt * 16 + ks) * 64 + lane) * 8;
      rh_[nt] = *(const bf16x8*)(AhL + ai);
      rl_[nt] = *(const bf16x8*)(AlL + ai);
    }
  };

  f32x16 acc[2][2];  // [code-tile][row-tile]
  auto mfmaStep = [&](const bf16x8* ch_, const bf16x8* cl_,
                      const bf16x8* rh_, const bf16x8* rl_) {
    __builtin_amdgcn_s_setprio(1);
#pragma unroll
    for (int ct = 0; ct < 2; ++ct)
#pragma unroll
      for (int nt = 0; nt < 2; ++nt) {
        acc[ct][nt] = __builtin_amdgcn_mfma_f32_32x32x16_bf16(
            ch_[ct], rh_[nt], acc[ct][nt], 0, 0, 0);
        acc[ct][nt] = __builtin_amdgcn_mfma_f32_32x32x16_bf16(
            ch_[ct], rl_[nt], acc[ct][nt], 0, 0, 0);
        acc[ct][nt] = __builtin_amdgcn_mfma_f32_32x32x16_bf16(
            cl_[ct], rh_[nt], acc[ct][nt], 0, 0, 0);
      }
    __builtin_amdgcn_s_setprio(0);
  };

  // Pipeline buffers (two named sets, compile-time alternation).
  bf16x8 Ach[2], Acl[2], Arh[2], Arl[2];
  bf16x8 Bch[2], Bcl[2], Brh[2], Brl[2];

  // Prologue: buffer A holds (ch=0, ks=0).
  loadCodes(0, 0, Ach, Acl);
  loadRows(0, Arh, Arl);

  for (int ch = 0; ch < 8; ++ch) {
    const int cb = wv * 512 + ch * 64;
#pragma unroll
    for (int ct = 0; ct < 2; ++ct)
#pragma unroll
      for (int nt = 0; nt < 2; ++nt)
#pragma unroll
        for (int e = 0; e < 16; ++e) acc[ct][nt][e] = 0.f;

    // Invariant at chunk entry: A = (ch, 0).
#pragma unroll
    for (int ks = 0; ks < 16; ks += 2) {
      // Slot A: prefetch (ch, ks+1) into B, compute ks from A.
      loadCodes(ch, ks + 1, Bch, Bcl);
      loadRows(ks + 1, Brh, Brl);
      mfmaStep(Ach, Acl, Arh, Arl);
      // Slot B: prefetch next (ch, ks+2) or (ch+1, 0) into A, compute ks+1.
      const int nch = (ks + 2 < 16) ? ch : (ch < 7 ? ch + 1 : 7);
      const int nks = (ks + 2 < 16) ? ks + 2 : 0;
      loadCodes(nch, nks, Ach, Acl);
      loadRows(nks, Arh, Arl);
      mfmaStep(Bch, Bcl, Brh, Brl);
    }

    // Epilogue: dist + lane-local top-2 per row.
    // acc[ct][nt][reg]: code = cb + ct*32 + (reg&3) + 8*(reg>>2) + go2*4,
    // row = nt*32 + (lane&31). Codes ascend per lane -> strict '<' keeps
    // first occurrence.
#pragma unroll
    for (int ct = 0; ct < 2; ++ct) {
#pragma unroll
      for (int reg = 0; reg < 16; ++reg) {
        const uint code = (uint)(cb + ct * 32 + (reg & 3) + 8 * (reg >> 2) +
                                 go2 * 4);
        const float en = enorm[code];
#pragma unroll
        for (int nt = 0; nt < 2; ++nt) {
          const float dd = fmaf(-2.f, acc[ct][nt][reg], en);
          if (dd < D1[nt]) {
            D2[nt] = D1[nt]; I2[nt] = I1[nt];
            D1[nt] = dd;     I1[nt] = code;
          } else if (dd < D2[nt]) {
            D2[nt] = dd;     I2[nt] = code;
          }
        }
      }
    }
  }

  // Merge lane pairs sharing a row (lane ^ 32 covers the other 4-code offset).
#pragma unroll
  for (int nt = 0; nt < 2; ++nt) {
    const float oD1 = __shfl_xor(D1[nt], 32, 64);
    const float oD2 = __shfl_xor(D2[nt], 32, 64);
    const uint  oI1 = (uint)__shfl_xor((int)I1[nt], 32, 64);
    const uint  oI2 = (uint)__shfl_xor((int)I2[nt], 32, 64);
    if (oD1 < D1[nt] || (oD1 == D1[nt] && oI1 < I1[nt])) {
      D2[nt] = D1[nt]; I2[nt] = I1[nt]; D1[nt] = oD1; I1[nt] = oI1;
    } else if (oD1 < D2[nt] || (oD1 == D2[nt] && oI1 < I2[nt])) {
      D2[nt] = oD1; I2[nt] = oI1;
    }
    if (oD2 < D1[nt] || (oD2 == D1[nt] && oI2 < I1[nt])) {
      D2[nt] = D1[nt]; I2[nt] = I1[nt]; D1[nt] = oD2; I1[nt] = oI2;
    } else if (oD2 < D2[nt] || (oD2 == D2[nt] && oI2 < I2[nt])) {
      D2[nt] = oD2; I2[nt] = oI2;
    }
  }

  // Cross-wave merge: 64 rows x 4 waves x 4 words = 4 KB in LDS.
  __syncthreads();  // done reading staged rows
  float* rdF = (float*)smem;
  uint*  rdI = smem;
  if (lane < 32) {
#pragma unroll
    for (int nt = 0; nt < 2; ++nt) {
      const int row  = nt * 32 + lane;
      const int base = (row * 4 + wv) * 4;
      rdF[base + 0] = D1[nt];
      rdI[base + 1] = I1[nt];
      rdF[base + 2] = D2[nt];
      rdI[base + 3] = I2[nt];
    }
  }
  __syncthreads();
  if (t < BM) {
    float d1 = 3.4e38f, d2 = 3.4e38f;
    uint  i1 = 0xFFFFu, i2 = 0xFFFFu;
#pragma unroll
    for (int s = 0; s < 4; ++s) {
      const int base = (t * 4 + s) * 4;
#pragma unroll
      for (int c = 0; c < 2; ++c) {
        const float d = rdF[base + c * 2];
        const uint  i = rdI[base + c * 2 + 1];
        if (d < d1 || (d == d1 && i < i1)) {
          d2 = d1; i2 = i1; d1 = d; i1 = i;
        } else if (d < d2 || (d == d2 && i < i2)) {
          d2 = d; i2 = i;
        }
      }
    }
    cand[r0 + t] = i1 | (i2 << 16);
  }
}

// ---------------------------------------------------------------------------
// Refine + gather + diff: exact fp32 distances for the 2 candidates, pick
// winner (first-occurrence tie-break), codebook lookup, straight-through
// output q = x + (e - x), per-block diff partial. Candidates are read from
// the idx_out region (bit-packed u32) and overwritten with the float index.
// ---------------------------------------------------------------------------
__global__ __launch_bounds__(256) void refine_gather_kernel(
    const float* __restrict__ inp, const float* __restrict__ embT,
    const float* __restrict__ enorm, float* __restrict__ q_out,
    float* __restrict__ idx_out, float* __restrict__ partials) {
  __shared__ float wsum[4];
  const int t    = threadIdx.x;
  const int row  = blockIdx.x * GROWS + (t >> 6);
  const int lane = t & 63;
  const int d4   = lane * 4;

  const uint u = ((const uint*)idx_out)[row];
  const int i1 = (int)(u & 0xFFFFu);
  const int i2 = (int)(u >> 16);

  const f32x4 x  = __builtin_nontemporal_load(
      (const f32x4*)(inp + (size_t)row * DIM + d4));
  const f32x4 e1 = *(const f32x4*)(embT + (size_t)i1 * DIM + d4);
  const f32x4 e2 = *(const f32x4*)(embT + (size_t)i2 * DIM + d4);

  float s1 = x[0] * e1[0] + x[1] * e1[1] + x[2] * e1[2] + x[3] * e1[3];
  float s2 = x[0] * e2[0] + x[1] * e2[1] + x[2] * e2[2] + x[3] * e2[3];
#pragma unroll
  for (int o = 32; o > 0; o >>= 1) {
    s1 += __shfl_xor(s1, o, 64);
    s2 += __shfl_xor(s2, o, 64);
  }
  const float dd1 = fmaf(-2.f, s1, enorm[i1]);
  const float dd2 = fmaf(-2.f, s2, enorm[i2]);
  const bool take2 = (dd2 < dd1) || (dd2 == dd1 && i2 < i1);
  const f32x4 e = take2 ? e2 : e1;
  const int  win = take2 ? i2 : i1;

  f32x4 dq, q;
  dq[0] = e[0] - x[0]; dq[1] = e[1] - x[1];
  dq[2] = e[2] - x[2]; dq[3] = e[3] - x[3];
  q[0] = x[0] + dq[0]; q[1] = x[1] + dq[1];
  q[2] = x[2] + dq[2]; q[3] = x[3] + dq[3];
  __builtin_nontemporal_store(q, (f32x4*)(q_out + (size_t)row * DIM + d4));
  if (lane == 0) idx_out[row] = (float)win;

  float s = dq[0] * dq[0] + dq[1] * dq[1] + dq[2] * dq[2] + dq[3] * dq[3];
#pragma unroll
  for (int o = 32; o > 0; o >>= 1) s += __shfl_down(s, o, 64);
  if (lane == 0) wsum[t >> 6] = s;
  __syncthreads();
  if (t == 0) partials[blockIdx.x] = wsum[0] + wsum[1] + wsum[2] + wsum[3];
}

// ---------------------------------------------------------------------------
__global__ __launch_bounds__(256) void final_diff_kernel(
    const float* __restrict__ partials, float* __restrict__ diff_out) {
  __shared__ float wsum[4];
  const int t = threadIdx.x;
  float s = 0.f;
  for (int k = 0; k < NBLK_RG / 256; ++k) s += partials[t + k * 256];
#pragma unroll
  for (int o = 32; o > 0; o >>= 1) s += __shfl_down(s, o, 64);
  if ((t & 63) == 0) wsum[t >> 6] = s;
  __syncthreads();
  if (t == 0) {
    const float total = wsum[0] + wsum[1] + wsum[2] + wsum[3];
    diff_out[0] = total * (1.0f / (float)((size_t)NROWS * DIM));
  }
}

// ---------------------------------------------------------------------------
extern "C" void kernel_launch(void* const* d_in, const int* in_sizes, int n_in,
                              void* d_out, int out_size, void* d_ws,
                              size_t ws_size, hipStream_t stream) {
  (void)in_sizes; (void)n_in; (void)out_size; (void)ws_size;
  const float* inp   = (const float*)d_in[0];
  const float* embed = (const float*)d_in[1];

  float* out      = (float*)d_out;
  float* q_out    = out;                        // 33554432 floats
  float* diff_out = out + (size_t)NROWS * DIM;  // 1 float
  float* idx_out  = diff_out + 1;               // 131072 floats (cand scratch)

  float* ws       = (float*)d_ws;
  float* embT     = ws;                          // 524288 floats (2 MB)
  float* enorm    = ws + (size_t)NE * DIM;       // 2048 floats
  float* partials = enorm + NE;                  // 32768 floats
  float* ebh      = partials + NBLK_RG;          // 262144 floats (1 MB as bf16)
  float* ebl      = ebh + (size_t)NE * DIM / 2;  // 262144 floats (1 MB as bf16)
  uint4* ebh4     = (uint4*)ebh;
  uint4* ebl4     = (uint4*)ebl;

  enorm_kernel<<<NE / 256, 256, 0, stream>>>(embed, enorm);
  transpose_kernel<<<dim3(NE / 32, DIM / 32), dim3(32, 8), 0, stream>>>(embed, embT);
  pack_embed_kernel<<<65536 / 256, 256, 0, stream>>>(embT, ebh4, ebl4);
  pass1_kernel<<<NBLK_P1, 256, 0, stream>>>(inp, ebh4, ebl4, enorm,
                                            (uint*)idx_out);
  refine_gather_kernel<<<NBLK_RG, 256, 0, stream>>>(inp, embT, enorm, q_out,
                                                    idx_out, partials);
  final_diff_kernel<<<1, 256, 0, stream>>>(partials, diff_out);
}

// Round 7
// 920.701 us; speedup vs baseline: 1.0031x; 1.0031x over previous
//
#include <hip/hip_runtime.h>
#include <cstdint>

// Problem: input [32,64,64,256] fp32 = 131072 rows x 256; embed [256,2048] fp32.
// d_out (fp32): quantize[33554432] | diff[1] | embed_ind_as_float[131072]
//
// Strategy: split-bf16 MFMA distance GEMM (xh+xl)(eh+el) with 3 MFMA terms,
// per-row top-2 candidate tracking, then exact fp32 refine of the 2 candidates
// fused with the gather/straight-through/diff epilogue.
//
// R1: NT loads on streaming input (kept).
// R3: swapped MFMA operands (codes=A/M, rows=B/N) -> lane-local top-2.
// R4: 32x32x16 MFMA -> halved fragments, 2 rows/lane state.
// R5/R6: explicit pipeline + waves_per_eu pin -> null (compiler reschedules;
//        occupancy pinned at 2 waves/SIMD by LDS 64KB AND 192-reg waves).
// R7: chunk widened to 128 codes (4 code-tiles). At a fixed 2 waves/SIMD,
//     latency must hide under per-wave ILP: 24 independent MFMA (~775
//     SIMD-cyc) per k-step now cover the ~200-300 cyc L2 latency of the
//     8 global b128 code loads. acc 128 + frags 48 + state ~8 fits the
//     256-reg budget that occupancy strands anyway. Floors: MFMA 165 us,
//     L2 codebook 119 us, LDS 78 us per CU -> target ~2x current.

#define NROWS   131072
#define DIM     256
#define NE      2048
#define BM      64                    // rows per pass1 block
#define NBLK_P1 (NROWS / BM)          // 2048
#define GROWS   4
#define NBLK_RG (NROWS / GROWS)       // 32768

typedef __attribute__((ext_vector_type(8))) short bf16x8;
typedef __attribute__((ext_vector_type(4))) float f32x4;
typedef __attribute__((ext_vector_type(16))) float f32x16;

__device__ __forceinline__ ushort bf16_rne(float v) {
  uint u = __float_as_uint(v);
  return (ushort)((u + 0x7FFFu + ((u >> 16) & 1u)) >> 16);
}
__device__ __forceinline__ void split_hi_lo(float v, ushort& h, ushort& l) {
  h = bf16_rne(v);
  const float hf = __uint_as_float(((uint)h) << 16);
  l = bf16_rne(v - hf);
}

// ---------------------------------------------------------------------------
// enorm[j] = sum_d embed[d][j]^2
// ---------------------------------------------------------------------------
__global__ __launch_bounds__(256) void enorm_kernel(
    const float* __restrict__ embed, float* __restrict__ enorm) {
  const int j = blockIdx.x * 256 + threadIdx.x;
  float s = 0.f;
#pragma unroll 8
  for (int d = 0; d < DIM; ++d) {
    const float v = embed[(size_t)d * NE + j];
    s = fmaf(v, v, s);
  }
  enorm[j] = s;
}

// ---------------------------------------------------------------------------
// embT[j][d] = embed[d][j]
// ---------------------------------------------------------------------------
__global__ __launch_bounds__(256) void transpose_kernel(
    const float* __restrict__ embed, float* __restrict__ embT) {
  __shared__ float tile[32][33];
  const int tx = threadIdx.x;  // 0..31
  const int ty = threadIdx.y;  // 0..7
  const int j0 = blockIdx.x * 32;
  const int d0 = blockIdx.y * 32;
#pragma unroll
  for (int i = 0; i < 4; ++i) {
    const int dd = ty + i * 8;
    tile[dd][tx] = embed[(size_t)(d0 + dd) * NE + j0 + tx];
  }
  __syncthreads();
#pragma unroll
  for (int i = 0; i < 4; ++i) {
    const int jj = ty + i * 8;
    embT[(size_t)(j0 + jj) * DIM + d0 + tx] = tile[tx][jj];
  }
}

// ---------------------------------------------------------------------------
// Pack embed into bf16 hi/lo in 32x32x16 MFMA fragment order:
// ebh4[(ct*16+ks)*64 + lane] = 8 bf16 of code ct*32+(lane&31),
//                              k = ks*16 + (lane>>5)*8 .. +7
// ---------------------------------------------------------------------------
__global__ __launch_bounds__(256) void pack_embed_kernel(
    const float* __restrict__ embT, uint4* __restrict__ ebh4,
    uint4* __restrict__ ebl4) {
  const int g    = blockIdx.x * 256 + threadIdx.x;  // 0..65535
  const int ct   = g >> 10;        // code tile of 32 (0..63)
  const int r    = g & 1023;
  const int ks   = r >> 6;         // k-step of 16 (0..15)
  const int lane = r & 63;
  const int code = ct * 32 + (lane & 31);
  const int k0   = ks * 16 + (lane >> 5) * 8;
  const float* src = embT + (size_t)code * DIM + k0;
  const float4 a = *(const float4*)(src);
  const float4 b = *(const float4*)(src + 4);
  ushort h[8], l[8];
  split_hi_lo(a.x, h[0], l[0]); split_hi_lo(a.y, h[1], l[1]);
  split_hi_lo(a.z, h[2], l[2]); split_hi_lo(a.w, h[3], l[3]);
  split_hi_lo(b.x, h[4], l[4]); split_hi_lo(b.y, h[5], l[5]);
  split_hi_lo(b.z, h[6], l[6]); split_hi_lo(b.w, h[7], l[7]);
  uint4 hv, lv;
  hv.x = (uint)h[0] | ((uint)h[1] << 16); hv.y = (uint)h[2] | ((uint)h[3] << 16);
  hv.z = (uint)h[4] | ((uint)h[5] << 16); hv.w = (uint)h[6] | ((uint)h[7] << 16);
  lv.x = (uint)l[0] | ((uint)l[1] << 16); lv.y = (uint)l[2] | ((uint)l[3] << 16);
  lv.z = (uint)l[4] | ((uint)l[5] << 16); lv.w = (uint)l[6] | ((uint)l[7] << 16);
  ebh4[g] = hv;
  ebl4[g] = lv;
}

// ---------------------------------------------------------------------------
// Pass 1: split-bf16 32x32x16 MFMA distance GEMM + per-row top-2.
// Block = 256 thr (4 waves), 64 rows staged in LDS (hi/lo, frag order).
// Wave w owns codes [w*512, w*512+512) in 4 chunks of 128 (4 code-tiles).
// Per k-step (K=16): 4 ds_read_b128 (rows) + 8 global b128 (codes, L2) +
// 24 independent MFMA -> ILP covers L2 latency at 2 waves/SIMD.
// dist = enorm[j] - 2*score. Merge: shfl_xor(32) + 4 KB LDS cross-wave.
// ---------------------------------------------------------------------------
__global__ __launch_bounds__(256)
__attribute__((amdgpu_waves_per_eu(2, 2))) void pass1_kernel(
    const float* __restrict__ inp, const uint4* __restrict__ ebh4,
    const uint4* __restrict__ ebl4, const float* __restrict__ enorm,
    uint* __restrict__ cand) {
  __shared__ __align__(16) uint smem[16384];  // 64 KB
  ushort* AhL = (ushort*)smem;                // 32 KB (input rows, hi)
  ushort* AlL = AhL + 16384;                  // 32 KB (input rows, lo)
  const int t  = threadIdx.x;
  const int r0 = blockIdx.x * BM;

  // Stage input rows: fp32 -> bf16 hi/lo, 32x32x16 fragment layout:
  // element (row, k): nt=row>>5, ks=k>>4, kh=(k>>3)&1, j=k&7
  // idx = ((nt*16+ks)*64 + (row&31) + kh*32)*8 + j
  {
    const int row = t >> 2, kq = t & 3;
    const int nt = row >> 5, r31 = row & 31;
    const f32x4* src = (const f32x4*)(inp + (size_t)(r0 + row) * DIM);
#pragma unroll 4
    for (int c = 0; c < 16; ++c) {
      const int k4 = c * 4 + kq;
      const f32x4 v = __builtin_nontemporal_load(src + k4);  // NT: stream input
      const int k = k4 * 4;
      const int ks = k >> 4, kh = (k >> 3) & 1, j = k & 7;
      const int idx = ((nt * 16 + ks) * 64 + r31 + kh * 32) * 8 + j;
      ushort h0, h1, h2, h3, l0, l1, l2, l3;
      split_hi_lo(v[0], h0, l0); split_hi_lo(v[1], h1, l1);
      split_hi_lo(v[2], h2, l2); split_hi_lo(v[3], h3, l3);
      ushort4 hv; hv.x = h0; hv.y = h1; hv.z = h2; hv.w = h3;
      ushort4 lv; lv.x = l0; lv.y = l1; lv.z = l2; lv.w = l3;
      *(ushort4*)(AhL + idx) = hv;
      *(ushort4*)(AlL + idx) = lv;
    }
  }
  __syncthreads();

  const int wv = t >> 6, lane = t & 63;
  const int go2 = lane >> 5;  // 4-code offset within reg-mapped codes

  // Per-lane top-2 state for 2 rows (row = nt*32 + (lane&31)): 8 regs.
  float D1[2], D2[2];
  uint  I1[2], I2[2];
#pragma unroll
  for (int i = 0; i < 2; ++i) {
    D1[i] = 3.4e38f; D2[i] = 3.4e38f; I1[i] = 0xFFFFu; I2[i] = 0xFFFFu;
  }

  for (int ch = 0; ch < 4; ++ch) {
    const int cb = wv * 512 + ch * 128;    // first code of this chunk
    const int ctb = wv * 16 + ch * 4;      // first code-tile (of 32)
    f32x16 acc[4][2];  // [code-tile][row-tile] = 128 regs
#pragma unroll
    for (int ct = 0; ct < 4; ++ct)
#pragma unroll
      for (int nt = 0; nt < 2; ++nt)
#pragma unroll
        for (int e = 0; e < 16; ++e) acc[ct][nt][e] = 0.f;

#pragma unroll
    for (int ks = 0; ks < 16; ++ks) {
      // Row fragments (B operand) from LDS: 4 x ds_read_b128
      bf16x8 rh[2], rl[2];
#pragma unroll
      for (int nt = 0; nt < 2; ++nt) {
        const int ai = ((nt * 16 + ks) * 64 + lane) * 8;
        rh[nt] = *(const bf16x8*)(AhL + ai);
        rl[nt] = *(const bf16x8*)(AlL + ai);
      }
      // Code fragments (A operand) from global (L2-resident): 8 x b128
      bf16x8 chf[4], clf[4];
#pragma unroll
      for (int ct = 0; ct < 4; ++ct) {
        const int bi = (ctb + ct) * 1024 + ks * 64 + lane;
        chf[ct] = *(const bf16x8*)(ebh4 + bi);
        clf[ct] = *(const bf16x8*)(ebl4 + bi);
      }
      __builtin_amdgcn_s_setprio(1);
#pragma unroll
      for (int ct = 0; ct < 4; ++ct)
#pragma unroll
        for (int nt = 0; nt < 2; ++nt) {
          acc[ct][nt] = __builtin_amdgcn_mfma_f32_32x32x16_bf16(
              chf[ct], rh[nt], acc[ct][nt], 0, 0, 0);
          acc[ct][nt] = __builtin_amdgcn_mfma_f32_32x32x16_bf16(
              chf[ct], rl[nt], acc[ct][nt], 0, 0, 0);
          acc[ct][nt] = __builtin_amdgcn_mfma_f32_32x32x16_bf16(
              clf[ct], rh[nt], acc[ct][nt], 0, 0, 0);
        }
      __builtin_amdgcn_s_setprio(0);
    }

    // Epilogue: dist + lane-local top-2 per row.
    // acc[ct][nt][reg]: code = cb + ct*32 + (reg&3) + 8*(reg>>2) + go2*4,
    // row = nt*32 + (lane&31). Codes ascend per lane over (ch,ct,reg) ->
    // strict '<' keeps first occurrence.
#pragma unroll
    for (int ct = 0; ct < 4; ++ct) {
#pragma unroll
      for (int reg = 0; reg < 16; ++reg) {
        const uint code = (uint)(cb + ct * 32 + (reg & 3) + 8 * (reg >> 2) +
                                 go2 * 4);
        const float en = enorm[code];
#pragma unroll
        for (int nt = 0; nt < 2; ++nt) {
          const float dd = fmaf(-2.f, acc[ct][nt][reg], en);
          if (dd < D1[nt]) {
            D2[nt] = D1[nt]; I2[nt] = I1[nt];
            D1[nt] = dd;     I1[nt] = code;
          } else if (dd < D2[nt]) {
            D2[nt] = dd;     I2[nt] = code;
          }
        }
      }
    }
  }

  // Merge lane pairs sharing a row (lane ^ 32 covers the other 4-code offset).
#pragma unroll
  for (int nt = 0; nt < 2; ++nt) {
    const float oD1 = __shfl_xor(D1[nt], 32, 64);
    const float oD2 = __shfl_xor(D2[nt], 32, 64);
    const uint  oI1 = (uint)__shfl_xor((int)I1[nt], 32, 64);
    const uint  oI2 = (uint)__shfl_xor((int)I2[nt], 32, 64);
    if (oD1 < D1[nt] || (oD1 == D1[nt] && oI1 < I1[nt])) {
      D2[nt] = D1[nt]; I2[nt] = I1[nt]; D1[nt] = oD1; I1[nt] = oI1;
    } else if (oD1 < D2[nt] || (oD1 == D2[nt] && oI1 < I2[nt])) {
      D2[nt] = oD1; I2[nt] = oI1;
    }
    if (oD2 < D1[nt] || (oD2 == D1[nt] && oI2 < I1[nt])) {
      D2[nt] = D1[nt]; I2[nt] = I1[nt]; D1[nt] = oD2; I1[nt] = oI2;
    } else if (oD2 < D2[nt] || (oD2 == D2[nt] && oI2 < I2[nt])) {
      D2[nt] = oD2; I2[nt] = oI2;
    }
  }

  // Cross-wave merge: 64 rows x 4 waves x 4 words = 4 KB in LDS.
  __syncthreads();  // done reading staged rows
  float* rdF = (float*)smem;
  uint*  rdI = smem;
  if (lane < 32) {
#pragma unroll
    for (int nt = 0; nt < 2; ++nt) {
      const int row  = nt * 32 + lane;
      const int base = (row * 4 + wv) * 4;
      rdF[base + 0] = D1[nt];
      rdI[base + 1] = I1[nt];
      rdF[base + 2] = D2[nt];
      rdI[base + 3] = I2[nt];
    }
  }
  __syncthreads();
  if (t < BM) {
    float d1 = 3.4e38f, d2 = 3.4e38f;
    uint  i1 = 0xFFFFu, i2 = 0xFFFFu;
#pragma unroll
    for (int s = 0; s < 4; ++s) {
      const int base = (t * 4 + s) * 4;
#pragma unroll
      for (int c = 0; c < 2; ++c) {
        const float d = rdF[base + c * 2];
        const uint  i = rdI[base + c * 2 + 1];
        if (d < d1 || (d == d1 && i < i1)) {
          d2 = d1; i2 = i1; d1 = d; i1 = i;
        } else if (d < d2 || (d == d2 && i < i2)) {
          d2 = d; i2 = i;
        }
      }
    }
    cand[r0 + t] = i1 | (i2 << 16);
  }
}

// ---------------------------------------------------------------------------
// Refine + gather + diff: exact fp32 distances for the 2 candidates, pick
// winner (first-occurrence tie-break), codebook lookup, straight-through
// output q = x + (e - x), per-block diff partial. Candidates are read from
// the idx_out region (bit-packed u32) and overwritten with the float index.
// ---------------------------------------------------------------------------
__global__ __launch_bounds__(256) void refine_gather_kernel(
    const float* __restrict__ inp, const float* __restrict__ embT,
    const float* __restrict__ enorm, float* __restrict__ q_out,
    float* __restrict__ idx_out, float* __restrict__ partials) {
  __shared__ float wsum[4];
  const int t    = threadIdx.x;
  const int row  = blockIdx.x * GROWS + (t >> 6);
  const int lane = t & 63;
  const int d4   = lane * 4;

  const uint u = ((const uint*)idx_out)[row];
  const int i1 = (int)(u & 0xFFFFu);
  const int i2 = (int)(u >> 16);

  const f32x4 x  = __builtin_nontemporal_load(
      (const f32x4*)(inp + (size_t)row * DIM + d4));
  const f32x4 e1 = *(const f32x4*)(embT + (size_t)i1 * DIM + d4);
  const f32x4 e2 = *(const f32x4*)(embT + (size_t)i2 * DIM + d4);

  float s1 = x[0] * e1[0] + x[1] * e1[1] + x[2] * e1[2] + x[3] * e1[3];
  float s2 = x[0] * e2[0] + x[1] * e2[1] + x[2] * e2[2] + x[3] * e2[3];
#pragma unroll
  for (int o = 32; o > 0; o >>= 1) {
    s1 += __shfl_xor(s1, o, 64);
    s2 += __shfl_xor(s2, o, 64);
  }
  const float dd1 = fmaf(-2.f, s1, enorm[i1]);
  const float dd2 = fmaf(-2.f, s2, enorm[i2]);
  const bool take2 = (dd2 < dd1) || (dd2 == dd1 && i2 < i1);
  const f32x4 e = take2 ? e2 : e1;
  const int  win = take2 ? i2 : i1;

  f32x4 dq, q;
  dq[0] = e[0] - x[0]; dq[1] = e[1] - x[1];
  dq[2] = e[2] - x[2]; dq[3] = e[3] - x[3];
  q[0] = x[0] + dq[0]; q[1] = x[1] + dq[1];
  q[2] = x[2] + dq[2]; q[3] = x[3] + dq[3];
  __builtin_nontemporal_store(q, (f32x4*)(q_out + (size_t)row * DIM + d4));
  if (lane == 0) idx_out[row] = (float)win;

  float s = dq[0] * dq[0] + dq[1] * dq[1] + dq[2] * dq[2] + dq[3] * dq[3];
#pragma unroll
  for (int o = 32; o > 0; o >>= 1) s += __shfl_down(s, o, 64);
  if (lane == 0) wsum[t >> 6] = s;
  __syncthreads();
  if (t == 0) partials[blockIdx.x] = wsum[0] + wsum[1] + wsum[2] + wsum[3];
}

// ---------------------------------------------------------------------------
__global__ __launch_bounds__(256) void final_diff_kernel(
    const float* __restrict__ partials, float* __restrict__ diff_out) {
  __shared__ float wsum[4];
  const int t = threadIdx.x;
  float s = 0.f;
  for (int k = 0; k < NBLK_RG / 256; ++k) s += partials[t + k * 256];
#pragma unroll
  for (int o = 32; o > 0; o >>= 1) s += __shfl_down(s, o, 64);
  if ((t & 63) == 0) wsum[t >> 6] = s;
  __syncthreads();
  if (t == 0) {
    const float total = wsum[0] + wsum[1] + wsum[2] + wsum[3];
    diff_out[0] = total * (1.0f / (float)((size_t)NROWS * DIM));
  }
}

// ---------------------------------------------------------------------------
extern "C" void kernel_launch(void* const* d_in, const int* in_sizes, int n_in,
                              void* d_out, int out_size, void* d_ws,
                              size_t ws_size, hipStream_t stream) {
  (void)in_sizes; (void)n_in; (void)out_size; (void)ws_size;
  const float* inp   = (const float*)d_in[0];
  const float* embed = (const float*)d_in[1];

  float* out      = (float*)d_out;
  float* q_out    = out;                        // 33554432 floats
  float* diff_out = out + (size_t)NROWS * DIM;  // 1 float
  float* idx_out  = diff_out + 1;               // 131072 floats (cand scratch)

  float* ws       = (float*)d_ws;
  float* embT     = ws;                          // 524288 floats (2 MB)
  float* enorm    = ws + (size_t)NE * DIM;       // 2048 floats
  float* partials = enorm + NE;                  // 32768 floats
  float* ebh      = partials + NBLK_RG;          // 262144 floats (1 MB as bf16)
  float* ebl      = ebh + (size_t)NE * DIM / 2;  // 262144 floats (1 MB as bf16)
  uint4* ebh4     = (uint4*)ebh;
  uint4* ebl4     = (uint4*)ebl;

  enorm_kernel<<<NE / 256, 256, 0, stream>>>(embed, enorm);
  transpose_kernel<<<dim3(NE / 32, DIM / 32), dim3(32, 8), 0, stream>>>(embed, embT);
  pack_embed_kernel<<<65536 / 256, 256, 0, stream>>>(embT, ebh4, ebl4);
  pass1_kernel<<<NBLK_P1, 256, 0, stream>>>(inp, ebh4, ebl4, enorm,
                                            (uint*)idx_out);
  refine_gather_kernel<<<NBLK_RG, 256, 0, stream>>>(inp, embT, enorm, q_out,
                                                    idx_out, partials);
  final_diff_kernel<<<1, 256, 0, stream>>>(partials, diff_out);
}